// Round 1
// baseline (631.376 us; speedup 1.0000x reference)
//
#include <hip/hip_runtime.h>

#define NV   100000
#define NE   20000
#define NNZT 1000000
#define DIM  64

// one wave per nnz entry: lane d handles feature d
__global__ __launch_bounds__(256) void scatter_v2e(
    const float* __restrict__ X,
    const int* __restrict__ vertex,
    const int* __restrict__ edges,
    float* __restrict__ Xe) {
    int w = blockIdx.x * 4 + (threadIdx.x >> 6);
    int lane = threadIdx.x & 63;
    if (w < NNZT) {
        int v = vertex[w];
        int e = edges[w];
        atomicAdd(&Xe[e * DIM + lane], X[v * DIM + lane]);
    }
}

__global__ __launch_bounds__(256) void scatter_e2v(
    const float* __restrict__ Xe,
    const int* __restrict__ vertex,
    const int* __restrict__ edges,
    float* __restrict__ Xv) {
    int w = blockIdx.x * 4 + (threadIdx.x >> 6);
    int lane = threadIdx.x & 63;
    if (w < NNZT) {
        int v = vertex[w];
        int e = edges[w];
        atomicAdd(&Xv[v * DIM + lane], Xe[e * DIM + lane]);
    }
}

// one wave per row: Xi = 0.5*Xv + 0.5*X0; h = relu(Xi@W1+b1); out = 0.5*Xi + 0.5*(h@W2+b2)
__global__ __launch_bounds__(256) void mlp_epilogue(
    const float* __restrict__ Xv,
    const float* __restrict__ X0,
    const float* __restrict__ W1,
    const float* __restrict__ b1,
    const float* __restrict__ W2,
    const float* __restrict__ b2,
    float* __restrict__ out) {
    __shared__ float sW1[DIM * DIM];
    __shared__ float sW2[DIM * DIM];
    __shared__ float srow[4][DIM];

    int tid = threadIdx.x;
    // cooperative load of W1, W2 into LDS (float4 vectorized)
    const float4* W1v = (const float4*)W1;
    const float4* W2v = (const float4*)W2;
    float4* sW1v = (float4*)sW1;
    float4* sW2v = (float4*)sW2;
    for (int i = tid; i < DIM * DIM / 4; i += 256) {
        sW1v[i] = W1v[i];
        sW2v[i] = W2v[i];
    }
    __syncthreads();

    int wave = tid >> 6;
    int lane = tid & 63;
    int row = blockIdx.x * 4 + wave;
    if (row >= NV) return;

    float xi = 0.5f * Xv[row * DIM + lane] + 0.5f * X0[row * DIM + lane];
    srow[wave][lane] = xi;
    __syncthreads();

    float h = b1[lane];
    #pragma unroll
    for (int k = 0; k < DIM; k++)
        h = fmaf(srow[wave][k], sW1[k * DIM + lane], h);
    h = fmaxf(h, 0.0f);

    __syncthreads();           // all lanes done reading xi row
    srow[wave][lane] = h;
    __syncthreads();

    float m = b2[lane];
    #pragma unroll
    for (int k = 0; k < DIM; k++)
        m = fmaf(srow[wave][k], sW2[k * DIM + lane], m);

    out[row * DIM + lane] = 0.5f * xi + 0.5f * m;
}

extern "C" void kernel_launch(void* const* d_in, const int* in_sizes, int n_in,
                              void* d_out, int out_size, void* d_ws, size_t ws_size,
                              hipStream_t stream) {
    const float* X  = (const float*)d_in[0];
    const float* X0 = (const float*)d_in[1];
    const float* W1 = (const float*)d_in[2];
    const float* b1 = (const float*)d_in[3];
    const float* W2 = (const float*)d_in[4];
    const float* b2 = (const float*)d_in[5];
    const int* vertex = (const int*)d_in[6];
    const int* edges  = (const int*)d_in[7];
    float* out = (float*)d_out;

    float* Xe = (float*)d_ws;                       // NE * DIM
    float* Xv = Xe + (size_t)NE * DIM;              // NV * DIM

    size_t zero_bytes = (size_t)(NE + NV) * DIM * sizeof(float);
    hipMemsetAsync(d_ws, 0, zero_bytes, stream);

    dim3 blk(256);
    dim3 grid_s((NNZT + 3) / 4);
    scatter_v2e<<<grid_s, blk, 0, stream>>>(X, vertex, edges, Xe);
    scatter_e2v<<<grid_s, blk, 0, stream>>>(Xe, vertex, edges, Xv);

    dim3 grid_m((NV + 3) / 4);
    mlp_epilogue<<<grid_m, blk, 0, stream>>>(Xv, X0, W1, b1, W2, b2, out);
}

// Round 2
// 588.559 us; speedup vs baseline: 1.0727x; 1.0727x over previous
//
#include <hip/hip_runtime.h>

#define NV   100000
#define NE   20000
#define NNZT 1000000
#define DIM  64

// ---------------- CSR build ----------------

// histogram of edge ids and vertex ids (int atomics, int4 loads)
__global__ __launch_bounds__(256) void hist_kernel(
    const int* __restrict__ vertex, const int* __restrict__ edges,
    int* __restrict__ ecnt, int* __restrict__ vcnt) {
    int i = blockIdx.x * 256 + threadIdx.x;
    if (i >= NNZT / 4) return;
    int4 v = ((const int4*)vertex)[i];
    int4 e = ((const int4*)edges)[i];
    atomicAdd(&ecnt[e.x], 1); atomicAdd(&ecnt[e.y], 1);
    atomicAdd(&ecnt[e.z], 1); atomicAdd(&ecnt[e.w], 1);
    atomicAdd(&vcnt[v.x], 1); atomicAdd(&vcnt[v.y], 1);
    atomicAdd(&vcnt[v.z], 1); atomicAdd(&vcnt[v.w], 1);
}

// exclusive scan of both count arrays: block 0 -> edges (NE), block 1 -> vertices (NV)
__global__ __launch_bounds__(1024) void scan_kernel(
    const int* __restrict__ ecnt, int* __restrict__ eoff,
    const int* __restrict__ vcnt, int* __restrict__ voff) {
    __shared__ int part[1024];
    const int* cnt; int* off; int n;
    if (blockIdx.x == 0) { cnt = ecnt; off = eoff; n = NE; }
    else                 { cnt = vcnt; off = voff; n = NV; }
    int tid = threadIdx.x;
    int per = (n + 1023) >> 10;
    int start = tid * per;
    int end = start + per; if (end > n) end = n;
    int sum = 0;
    for (int i = start; i < end && i >= 0; i++) sum += cnt[i];
    part[tid] = sum;
    __syncthreads();
    for (int ofs = 1; ofs < 1024; ofs <<= 1) {
        int v = (tid >= ofs) ? part[tid - ofs] : 0;
        __syncthreads();
        part[tid] += v;
        __syncthreads();
    }
    int run = part[tid] - sum;   // exclusive base
    for (int i = start; i < end; i++) { off[i] = run; run += cnt[i]; }
    if (end == n) off[n] = run;  // multiple writers, same value (= NNZ)
}

// scatter entries into CSR slot lists using atomic position counters
__global__ __launch_bounds__(256) void build_kernel(
    const int* __restrict__ vertex, const int* __restrict__ edges,
    const int* __restrict__ eoff, const int* __restrict__ voff,
    int* __restrict__ ecur, int* __restrict__ vcur,
    int* __restrict__ eperm, int* __restrict__ vperm) {
    int i = blockIdx.x * 256 + threadIdx.x;
    if (i >= NNZT / 4) return;
    int4 v = ((const int4*)vertex)[i];
    int4 e = ((const int4*)edges)[i];
    int p, q;
    p = atomicAdd(&ecur[e.x], 1); eperm[eoff[e.x] + p] = v.x;
    q = atomicAdd(&vcur[v.x], 1); vperm[voff[v.x] + q] = e.x;
    p = atomicAdd(&ecur[e.y], 1); eperm[eoff[e.y] + p] = v.y;
    q = atomicAdd(&vcur[v.y], 1); vperm[voff[v.y] + q] = e.y;
    p = atomicAdd(&ecur[e.z], 1); eperm[eoff[e.z] + p] = v.z;
    q = atomicAdd(&vcur[v.z], 1); vperm[voff[v.z] + q] = e.z;
    p = atomicAdd(&ecur[e.w], 1); eperm[eoff[e.w] + p] = v.w;
    q = atomicAdd(&vcur[v.w], 1); vperm[voff[v.w] + q] = e.w;
}

// ---------------- aggregation ----------------

// one wave per edge: Xe[e] = sum_{v in edge e} X[v]
__global__ __launch_bounds__(256) void agg_edges(
    const float* __restrict__ X,
    const int* __restrict__ eoff, const int* __restrict__ eperm,
    float* __restrict__ Xe) {
    int wave = threadIdx.x >> 6, lane = threadIdx.x & 63;
    int e = blockIdx.x * 4 + wave;           // NE % 4 == 0, no tail
    int beg = eoff[e], end = eoff[e + 1];
    float acc = 0.f;
    int j = beg;
    for (; j + 4 <= end; j += 4) {
        int v0 = eperm[j], v1 = eperm[j + 1], v2 = eperm[j + 2], v3 = eperm[j + 3];
        float a = X[v0 * DIM + lane];
        float b = X[v1 * DIM + lane];
        float c = X[v2 * DIM + lane];
        float d = X[v3 * DIM + lane];
        acc += (a + b) + (c + d);
    }
    for (; j < end; j++) acc += X[eperm[j] * DIM + lane];
    Xe[e * DIM + lane] = acc;
}

// one wave per vertex (grid-stride): Xv gather + jump-link + 2-layer MLP, fused
__global__ __launch_bounds__(256) void agg_verts_mlp(
    const float* __restrict__ Xe, const float* __restrict__ X0,
    const float* __restrict__ W1, const float* __restrict__ b1,
    const float* __restrict__ W2, const float* __restrict__ b2,
    const int* __restrict__ voff, const int* __restrict__ vperm,
    float* __restrict__ out) {
    __shared__ float sW1[DIM * DIM];
    __shared__ float sW2[DIM * DIM];
    __shared__ float srow[4][DIM];
    __shared__ float shid[4][DIM];

    int tid = threadIdx.x;
    const float4* W1v = (const float4*)W1;
    const float4* W2v = (const float4*)W2;
    float4* sW1v = (float4*)sW1;
    float4* sW2v = (float4*)sW2;
    for (int i = tid; i < DIM * DIM / 4; i += 256) {
        sW1v[i] = W1v[i];
        sW2v[i] = W2v[i];
    }
    __syncthreads();

    int wave = tid >> 6, lane = tid & 63;
    float bb1 = b1[lane], bb2 = b2[lane];

    for (int g = blockIdx.x; g < NV / 4; g += gridDim.x) {
        int row = g * 4 + wave;              // NV % 4 == 0, no tail
        int beg = voff[row], end = voff[row + 1];
        float acc = 0.f;
        int j = beg;
        for (; j + 4 <= end; j += 4) {
            int e0 = vperm[j], e1 = vperm[j + 1], e2 = vperm[j + 2], e3 = vperm[j + 3];
            float a = Xe[e0 * DIM + lane];
            float b = Xe[e1 * DIM + lane];
            float c = Xe[e2 * DIM + lane];
            float d = Xe[e3 * DIM + lane];
            acc += (a + b) + (c + d);
        }
        for (; j < end; j++) acc += Xe[vperm[j] * DIM + lane];

        float xi = 0.5f * acc + 0.5f * X0[row * DIM + lane];

        // wave-synchronous LDS row broadcast (no cross-wave deps)
        srow[wave][lane] = xi;
        __builtin_amdgcn_wave_barrier();
        float h = bb1;
        #pragma unroll
        for (int k = 0; k < DIM; k++)
            h = fmaf(srow[wave][k], sW1[k * DIM + lane], h);
        h = fmaxf(h, 0.f);

        shid[wave][lane] = h;
        __builtin_amdgcn_wave_barrier();
        float m = bb2;
        #pragma unroll
        for (int k = 0; k < DIM; k++)
            m = fmaf(shid[wave][k], sW2[k * DIM + lane], m);

        out[row * DIM + lane] = 0.5f * xi + 0.5f * m;
    }
}

extern "C" void kernel_launch(void* const* d_in, const int* in_sizes, int n_in,
                              void* d_out, int out_size, void* d_ws, size_t ws_size,
                              hipStream_t stream) {
    const float* X  = (const float*)d_in[0];
    const float* X0 = (const float*)d_in[1];
    const float* W1 = (const float*)d_in[2];
    const float* b1 = (const float*)d_in[3];
    const float* W2 = (const float*)d_in[4];
    const float* b2 = (const float*)d_in[5];
    const int* vertex = (const int*)d_in[6];
    const int* edges  = (const int*)d_in[7];
    float* out = (float*)d_out;

    // workspace layout (ints unless noted)
    int* ecnt  = (int*)d_ws;                 // NE
    int* vcnt  = ecnt + NE;                  // NV
    int* ecur  = vcnt + NV;                  // NE
    int* vcur  = ecur + NE;                  // NV
    int* eoff  = vcur + NV;                  // NE+1
    int* voff  = eoff + NE + 1;              // NV+1
    int* eperm = voff + NV + 1;              // NNZ
    int* vperm = eperm + NNZT;               // NNZ
    float* Xe  = (float*)(vperm + NNZT);     // NE*DIM floats

    // zero the four counter arrays only
    hipMemsetAsync(d_ws, 0, (size_t)(2 * (NE + NV)) * sizeof(int), stream);

    dim3 blk(256);
    int nq = NNZT / 4;
    dim3 grid_q((nq + 255) / 256);
    hist_kernel<<<grid_q, blk, 0, stream>>>(vertex, edges, ecnt, vcnt);
    scan_kernel<<<2, 1024, 0, stream>>>(ecnt, eoff, vcnt, voff);
    build_kernel<<<grid_q, blk, 0, stream>>>(vertex, edges, eoff, voff,
                                             ecur, vcur, eperm, vperm);

    agg_edges<<<NE / 4, blk, 0, stream>>>(X, eoff, eperm, Xe);

    agg_verts_mlp<<<1024, blk, 0, stream>>>(Xe, X0, W1, b1, W2, b2,
                                            voff, vperm, out);
}

// Round 3
// 486.056 us; speedup vs baseline: 1.2990x; 1.2109x over previous
//
#include <hip/hip_runtime.h>

#define NV   100000
#define NE   20000
#define NNZT 1000000
#define DIM  64

// ---------------- CSR build ----------------

// histogram of edge ids and vertex ids (int atomics, int4 loads)
__global__ __launch_bounds__(256) void hist_kernel(
    const int* __restrict__ vertex, const int* __restrict__ edges,
    int* __restrict__ ecnt, int* __restrict__ vcnt) {
    int i = blockIdx.x * 256 + threadIdx.x;
    if (i >= NNZT / 4) return;
    int4 v = ((const int4*)vertex)[i];
    int4 e = ((const int4*)edges)[i];
    atomicAdd(&ecnt[e.x], 1); atomicAdd(&ecnt[e.y], 1);
    atomicAdd(&ecnt[e.z], 1); atomicAdd(&ecnt[e.w], 1);
    atomicAdd(&vcnt[v.x], 1); atomicAdd(&vcnt[v.y], 1);
    atomicAdd(&vcnt[v.z], 1); atomicAdd(&vcnt[v.w], 1);
}

// block-local scan + one atomic range-grab per block.
// CSR ranges are disjoint but NOT in index order — aggregation doesn't care.
#define EBLK ((NE + 255) / 256)
#define VBLK ((NV + 255) / 256)
__global__ __launch_bounds__(256) void offsets_kernel(
    const int* __restrict__ ecnt, const int* __restrict__ vcnt,
    int* __restrict__ ebase, int* __restrict__ vbase,
    int* __restrict__ ecur, int* __restrict__ vcur,
    int* __restrict__ gtot) {
    __shared__ int s[256];
    __shared__ int sbase;
    int tid = threadIdx.x;
    const int* cnt; int* basep; int* curp; int n, idx0, which;
    if (blockIdx.x < EBLK) {
        cnt = ecnt; basep = ebase; curp = ecur; n = NE;
        idx0 = blockIdx.x * 256; which = 0;
    } else {
        cnt = vcnt; basep = vbase; curp = vcur; n = NV;
        idx0 = (blockIdx.x - EBLK) * 256; which = 1;
    }
    int i = idx0 + tid;
    int c = (i < n) ? cnt[i] : 0;
    // Hillis-Steele inclusive scan in LDS
    s[tid] = c;
    __syncthreads();
    int val = c;
    for (int ofs = 1; ofs < 256; ofs <<= 1) {
        int t = (tid >= ofs) ? s[tid - ofs] : 0;
        __syncthreads();
        val += t;
        s[tid] = val;
        __syncthreads();
    }
    if (tid == 255) sbase = atomicAdd(&gtot[which], val);  // block sum
    __syncthreads();
    if (i < n) {
        int b = sbase + (val - c);   // exclusive prefix within block
        basep[i] = b;
        curp[i] = b;
    }
}

// scatter entries into CSR slot lists; cur arrays hold absolute slots
__global__ __launch_bounds__(256) void build_kernel(
    const int* __restrict__ vertex, const int* __restrict__ edges,
    int* __restrict__ ecur, int* __restrict__ vcur,
    int* __restrict__ eperm, int* __restrict__ vperm) {
    int i = blockIdx.x * 256 + threadIdx.x;
    if (i >= NNZT / 4) return;
    int4 v = ((const int4*)vertex)[i];
    int4 e = ((const int4*)edges)[i];
    int p, q;
    p = atomicAdd(&ecur[e.x], 1); eperm[p] = v.x;
    q = atomicAdd(&vcur[v.x], 1); vperm[q] = e.x;
    p = atomicAdd(&ecur[e.y], 1); eperm[p] = v.y;
    q = atomicAdd(&vcur[v.y], 1); vperm[q] = e.y;
    p = atomicAdd(&ecur[e.z], 1); eperm[p] = v.z;
    q = atomicAdd(&vcur[v.z], 1); vperm[q] = e.z;
    p = atomicAdd(&ecur[e.w], 1); eperm[p] = v.w;
    q = atomicAdd(&vcur[v.w], 1); vperm[q] = e.w;
}

// ---------------- aggregation ----------------

// one wave per edge: Xe[e] = sum_{v in edge e} X[v]
__global__ __launch_bounds__(256) void agg_edges(
    const float* __restrict__ X,
    const int* __restrict__ ebase, const int* __restrict__ ecnt,
    const int* __restrict__ eperm,
    float* __restrict__ Xe) {
    int wave = threadIdx.x >> 6, lane = threadIdx.x & 63;
    int e = blockIdx.x * 4 + wave;           // NE % 4 == 0, no tail
    int beg = ebase[e], end = beg + ecnt[e];
    float acc = 0.f;
    int j = beg;
    for (; j + 4 <= end; j += 4) {
        int v0 = eperm[j], v1 = eperm[j + 1], v2 = eperm[j + 2], v3 = eperm[j + 3];
        float a = X[v0 * DIM + lane];
        float b = X[v1 * DIM + lane];
        float c = X[v2 * DIM + lane];
        float d = X[v3 * DIM + lane];
        acc += (a + b) + (c + d);
    }
    for (; j < end; j++) acc += X[eperm[j] * DIM + lane];
    Xe[e * DIM + lane] = acc;
}

// one wave per vertex (grid-stride): Xv gather + jump-link + 2-layer MLP, fused
__global__ __launch_bounds__(256) void agg_verts_mlp(
    const float* __restrict__ Xe, const float* __restrict__ X0,
    const float* __restrict__ W1, const float* __restrict__ b1,
    const float* __restrict__ W2, const float* __restrict__ b2,
    const int* __restrict__ vbase, const int* __restrict__ vcnt,
    const int* __restrict__ vperm,
    float* __restrict__ out) {
    __shared__ float sW1[DIM * DIM];
    __shared__ float sW2[DIM * DIM];
    __shared__ float srow[4][DIM];
    __shared__ float shid[4][DIM];

    int tid = threadIdx.x;
    const float4* W1v = (const float4*)W1;
    const float4* W2v = (const float4*)W2;
    float4* sW1v = (float4*)sW1;
    float4* sW2v = (float4*)sW2;
    for (int i = tid; i < DIM * DIM / 4; i += 256) {
        sW1v[i] = W1v[i];
        sW2v[i] = W2v[i];
    }
    __syncthreads();

    int wave = tid >> 6, lane = tid & 63;
    float bb1 = b1[lane], bb2 = b2[lane];

    for (int g = blockIdx.x; g < NV / 4; g += gridDim.x) {
        int row = g * 4 + wave;              // NV % 4 == 0, no tail
        int beg = vbase[row], end = beg + vcnt[row];
        float acc = 0.f;
        int j = beg;
        for (; j + 4 <= end; j += 4) {
            int e0 = vperm[j], e1 = vperm[j + 1], e2 = vperm[j + 2], e3 = vperm[j + 3];
            float a = Xe[e0 * DIM + lane];
            float b = Xe[e1 * DIM + lane];
            float c = Xe[e2 * DIM + lane];
            float d = Xe[e3 * DIM + lane];
            acc += (a + b) + (c + d);
        }
        for (; j < end; j++) acc += Xe[vperm[j] * DIM + lane];

        float xi = 0.5f * acc + 0.5f * X0[row * DIM + lane];

        // wave-synchronous LDS row broadcast (no cross-wave deps)
        srow[wave][lane] = xi;
        __builtin_amdgcn_wave_barrier();
        float h = bb1;
        #pragma unroll
        for (int k = 0; k < DIM; k++)
            h = fmaf(srow[wave][k], sW1[k * DIM + lane], h);
        h = fmaxf(h, 0.f);

        shid[wave][lane] = h;
        __builtin_amdgcn_wave_barrier();
        float m = bb2;
        #pragma unroll
        for (int k = 0; k < DIM; k++)
            m = fmaf(shid[wave][k], sW2[k * DIM + lane], m);

        out[row * DIM + lane] = 0.5f * xi + 0.5f * m;
    }
}

extern "C" void kernel_launch(void* const* d_in, const int* in_sizes, int n_in,
                              void* d_out, int out_size, void* d_ws, size_t ws_size,
                              hipStream_t stream) {
    const float* X  = (const float*)d_in[0];
    const float* X0 = (const float*)d_in[1];
    const float* W1 = (const float*)d_in[2];
    const float* b1 = (const float*)d_in[3];
    const float* W2 = (const float*)d_in[4];
    const float* b2 = (const float*)d_in[5];
    const int* vertex = (const int*)d_in[6];
    const int* edges  = (const int*)d_in[7];
    float* out = (float*)d_out;

    // workspace layout (ints unless noted); first (NE+NV+2) ints get memset to 0
    int* ecnt  = (int*)d_ws;                 // NE
    int* vcnt  = ecnt + NE;                  // NV
    int* gtot  = vcnt + NV;                  // 2
    int* ebase = gtot + 2;                   // NE
    int* vbase = ebase + NE;                 // NV
    int* ecur  = vbase + NV;                 // NE
    int* vcur  = ecur + NE;                  // NV
    int* eperm = vcur + NV;                  // NNZ
    int* vperm = eperm + NNZT;               // NNZ
    float* Xe  = (float*)(vperm + NNZT);     // NE*DIM floats

    hipMemsetAsync(d_ws, 0, (size_t)(NE + NV + 2) * sizeof(int), stream);

    dim3 blk(256);
    int nq = NNZT / 4;
    dim3 grid_q((nq + 255) / 256);
    hist_kernel<<<grid_q, blk, 0, stream>>>(vertex, edges, ecnt, vcnt);
    offsets_kernel<<<EBLK + VBLK, blk, 0, stream>>>(ecnt, vcnt, ebase, vbase,
                                                    ecur, vcur, gtot);
    build_kernel<<<grid_q, blk, 0, stream>>>(vertex, edges, ecur, vcur,
                                             eperm, vperm);

    agg_edges<<<NE / 4, blk, 0, stream>>>(X, ebase, ecnt, eperm, Xe);

    agg_verts_mlp<<<1024, blk, 0, stream>>>(Xe, X0, W1, b1, W2, b2,
                                            vbase, vcnt, vperm, out);
}